// Round 11
// baseline (4329.373 us; speedup 1.0000x reference)
//
#include <hip/hip_runtime.h>

// SLULatticeRNN: B=32, S=256, K=3, D=H=512, 4H=2048, L=128.
// recur11: TAG-FREE stamped exchange. h published as 64-bit relaxed agent
// atomics: (stamp=t+1)<<32 | 2xbf16. Consumer gathers + checks stamps;
// retries stale rows (syncthreads_and loop). No tags, no watermarks, no
// validation machinery. Counted vmcnt(24) end-of-step drain (c-store only;
// 24 gather loads fly across the barrier). h_hist memset(0) per launch.
// c_hist overlays dead prep buffers (Xb/Wihb/bias) -> 64 MB total ws.

#define BB 32
#define SS 256
#define KKK 3
#define DD 512
#define HH 512
#define G4 2048
#define LL 128
#define NG 2    // batch groups
#define GS 8    // slice blocks per group
#define NB 16   // batches per group
#define HSL 64  // h dims per slice block

typedef __attribute__((ext_vector_type(4))) float f32x4;
typedef __attribute__((ext_vector_type(8))) short bf16x8;

__device__ __forceinline__ float blo(unsigned u){ return __builtin_bit_cast(float, u << 16); }
__device__ __forceinline__ float bhi(unsigned u){ return __builtin_bit_cast(float, u & 0xffff0000u); }
__device__ __forceinline__ unsigned f2bf(float f){
  unsigned x = __builtin_bit_cast(unsigned, f);
  x = x + 0x7fffu + ((x >> 16) & 1u);
  return x >> 16;
}
__device__ __forceinline__ float sigm(float x){ return 1.0f / (1.0f + __expf(-x)); }
__device__ __forceinline__ float tanh_(float x){
  float ax = fabsf(x);
  float e = __expf(-2.0f * ax);
  float r = (1.0f - e) / (1.0f + e);
  return x < 0.0f ? -r : r;
}
__device__ __forceinline__ void glds16(const void* g, void* lds){
  __builtin_amdgcn_global_load_lds((const __attribute__((address_space(1))) unsigned int*)g,
                                   (__attribute__((address_space(3))) unsigned int*)lds, 16, 0, 0);
}

// ---------------- prep: X gather->bf16, Wih->bf16, bias ----------------
__global__ __launch_bounds__(256) void prep_kernel(
    const int* __restrict__ inputs, const float* __restrict__ emb,
    const float* __restrict__ Wih, const float* __restrict__ bih, const float* __restrict__ bhh,
    unsigned short* __restrict__ Xb, unsigned short* __restrict__ Wihb, float* __restrict__ bias)
{
  int blk = blockIdx.x, tid = threadIdx.x;
  if (blk < 512){
    int row = blk * 16 + (tid >> 4);       // m = t*32+b
    int d0 = (tid & 15) * 32;
    int b = row & 31, t = row >> 5;
    int tok = inputs[b * SS + t];
    const float* src = emb + (size_t)tok * DD + d0;
    unsigned short* dst = Xb + (size_t)row * DD + d0;
    #pragma unroll
    for (int j = 0; j < 32; j += 4){
      float4 v = *(const float4*)(src + j);
      uint2 o;
      o.x = f2bf(v.x) | (f2bf(v.y) << 16);
      o.y = f2bf(v.z) | (f2bf(v.w) << 16);
      *(uint2*)(dst + j) = o;
    }
  } else if (blk < 640){
    int row = (blk - 512) * 16 + (tid >> 4);
    int d0 = (tid & 15) * 32;
    const float* src = Wih + (size_t)row * DD + d0;
    unsigned short* dst = Wihb + (size_t)row * DD + d0;
    #pragma unroll
    for (int j = 0; j < 32; j += 4){
      float4 v = *(const float4*)(src + j);
      uint2 o;
      o.x = f2bf(v.x) | (f2bf(v.y) << 16);
      o.y = f2bf(v.z) | (f2bf(v.w) << 16);
      *(uint2*)(dst + j) = o;
    }
  } else {
    for (int n = tid; n < G4; n += 256) bias[n] = bih[n] + bhh[n];
  }
}

// ---------------- gemm_gx: gates_x[m][n] = X[m]·Wih[n] + bias[n], bf16 out ----------------
__global__ __launch_bounds__(256) void gemm_gx(
    const unsigned short* __restrict__ Xb, const unsigned short* __restrict__ Wihb,
    const float* __restrict__ bias, unsigned short* __restrict__ gx)
{
  __shared__ unsigned short As[128 * 32];
  __shared__ unsigned short Bs[128 * 32];
  const int tid = threadIdx.x;
  const int lane = tid & 63, wid = tid >> 6;
  const int m0 = blockIdx.x * 128, n0 = blockIdx.y * 128;
  const int wm = wid & 1, wn = wid >> 1;
  f32x4 acc[4][4];
  #pragma unroll
  for (int i = 0; i < 4; i++)
    #pragma unroll
    for (int j = 0; j < 4; j++)
      acc[i][j] = (f32x4){0.f, 0.f, 0.f, 0.f};

  for (int kk = 0; kk < DD; kk += 32){
    #pragma unroll
    for (int r = 0; r < 2; r++){
      int q = r * 256 + wid * 64 + lane;
      int row = q >> 2, seg = q & 3;
      glds16(Xb   + (size_t)(m0 + row) * DD + kk + seg * 8, As + (size_t)(r * 256 + wid * 64) * 8);
      glds16(Wihb + (size_t)(n0 + row) * DD + kk + seg * 8, Bs + (size_t)(r * 256 + wid * 64) * 8);
    }
    __syncthreads();
    bf16x8 af[4], bfv[4];
    #pragma unroll
    for (int i = 0; i < 4; i++){
      int ra = wm * 64 + i * 16 + (lane & 15);
      af[i] = *(const bf16x8*)(As + ra * 32 + (lane >> 4) * 8);
      int rb = wn * 64 + i * 16 + (lane & 15);
      bfv[i] = *(const bf16x8*)(Bs + rb * 32 + (lane >> 4) * 8);
    }
    #pragma unroll
    for (int i = 0; i < 4; i++)
      #pragma unroll
      for (int j = 0; j < 4; j++)
        acc[i][j] = __builtin_amdgcn_mfma_f32_16x16x32_bf16(af[i], bfv[j], acc[i][j], 0, 0, 0);
    __syncthreads();
  }
  #pragma unroll
  for (int j = 0; j < 4; j++){
    int ncol = n0 + wn * 64 + j * 16 + (lane & 15);
    float bv = bias[ncol];
    #pragma unroll
    for (int i = 0; i < 4; i++){
      int mbase = m0 + wm * 64 + i * 16 + (lane >> 4) * 4;
      #pragma unroll
      for (int r = 0; r < 4; r++)
        gx[(size_t)(mbase + r) * G4 + ncol] = (unsigned short)f2bf(acc[i][j][r] + bv);
    }
  }
}

// ---------------- recur11 ----------------
// grid = 16 x 512. grp = bid>>3 (16 batches), g = bid&7 (64-dim h slice).
// h_hist [SS][NG][GS][NB][32 pairs] u64: (stamp=t+1)<<32 | (2xbf16 data).
//   Relaxed agent atomics only. memset(0) per launch (stamp 0 = invalid).
// c_hist [16][SS][NB][HSL] f32: block-private, plain cached.
__global__ __launch_bounds__(512, 1) void recur11(
    const int* __restrict__ prev_idx, const float* __restrict__ prev_w,
    const float* __restrict__ Whh, const int* __restrict__ positions,
    const unsigned short* __restrict__ gx,
    unsigned long long* __restrict__ h_hist, float* __restrict__ c_hist,
    float* __restrict__ pooled)
{
  __shared__ __align__(16) unsigned char hA[16 * 1024];  // h~ [16b][512] bf16, XOR-swizzled
  __shared__ float gex[NB][264];
  __shared__ float wst2[2][NB * 3];
  __shared__ int   ist2[2][NB * 3];

  const int tid = threadIdx.x;
  const int lane = tid & 63, w = tid >> 6;
  const int bid = blockIdx.x, grp = bid >> 3, g = bid & 7;

  // ---- persistent B-fragments: Whh rows {q*512 + g*64 + [0,64)} ----
  bf16x8 bfr0[16], bfr1[16];
  #pragma unroll
  for (int kf = 0; kf < 16; kf++){
    #pragma unroll
    for (int i = 0; i < 2; i++){
      int nt = 2 * w + i;
      int grow = (nt >> 2) * HH + g * HSL + ((nt & 3) << 4) + (lane & 15);
      int kcol = kf * 32 + ((lane >> 4) << 3);
      const float* p = Whh + (size_t)grow * HH + kcol;
      float4 v0 = *(const float4*)p;
      float4 v1 = *(const float4*)(p + 4);
      bf16x8 tf;
      tf[0] = (short)f2bf(v0.x); tf[1] = (short)f2bf(v0.y);
      tf[2] = (short)f2bf(v0.z); tf[3] = (short)f2bf(v0.w);
      tf[4] = (short)f2bf(v1.x); tf[5] = (short)f2bf(v1.y);
      tf[6] = (short)f2bf(v1.z); tf[7] = (short)f2bf(v1.w);
      if (i == 0) bfr0[kf] = tf; else bfr1[kf] = tf;
    }
  }

  // mappings
  const int cb = tid >> 5;             // local batch (elementwise)
  const int jd = (tid & 31) << 1;      // dim pair within slice
  const int bg = grp * NB + cb;
  const int gq = tid & 15;             // batch (gather)
  const int gd = tid >> 4;             // 16-dim chunk of 512
  const int ggs = gd >> 2;             // peer slice
  const int gpo = (gd & 3) << 3;       // pair offset within slice (8 pairs/chunk)

  const int st = positions[bg * 2], en = positions[bg * 2 + 1];
  float pm0 = -1e30f, pm1 = -1e30f;
  const size_t cblk = (size_t)bid * ((size_t)SS * NB * HSL);

  // prefetch registers (statically indexed)
  unsigned long long dq0[8], dq1[8], dq2[8];
  float2 cg0, cg1, cg2;
  unsigned gxv0, gxv1, gxv2, gxv3;

  auto issue_gather = [&](int slot){
    int i0 = ist2[slot][gq * 3], i1 = ist2[slot][gq * 3 + 1], i2 = ist2[slot][gq * 3 + 2];
    size_t s0 = ((((size_t)i0 * NG + grp) * GS + ggs) * NB + gq) * 32 + gpo;
    size_t s1 = ((((size_t)i1 * NG + grp) * GS + ggs) * NB + gq) * 32 + gpo;
    size_t s2 = ((((size_t)i2 * NG + grp) * GS + ggs) * NB + gq) * 32 + gpo;
    #pragma unroll
    for (int j = 0; j < 8; j++)
      dq0[j] = __hip_atomic_load(h_hist + s0 + j, __ATOMIC_RELAXED, __HIP_MEMORY_SCOPE_AGENT);
    #pragma unroll
    for (int j = 0; j < 8; j++)
      dq1[j] = __hip_atomic_load(h_hist + s1 + j, __ATOMIC_RELAXED, __HIP_MEMORY_SCOPE_AGENT);
    #pragma unroll
    for (int j = 0; j < 8; j++)
      dq2[j] = __hip_atomic_load(h_hist + s2 + j, __ATOMIC_RELAXED, __HIP_MEMORY_SCOPE_AGENT);
  };
  auto check_stamps = [&](int slot)->bool{
    unsigned w0 = (unsigned)(ist2[slot][gq * 3]     + 1);
    unsigned w1 = (unsigned)(ist2[slot][gq * 3 + 1] + 1);
    unsigned w2 = (unsigned)(ist2[slot][gq * 3 + 2] + 1);
    bool ok = true;
    #pragma unroll
    for (int j = 0; j < 8; j++) ok = ok && ((unsigned)(dq0[j] >> 32) == w0);
    #pragma unroll
    for (int j = 0; j < 8; j++) ok = ok && ((unsigned)(dq1[j] >> 32) == w1);
    #pragma unroll
    for (int j = 0; j < 8; j++) ok = ok && ((unsigned)(dq2[j] >> 32) == w2);
    return ok;
  };
  auto issue_cgx = [&](int slot, int tn){
    const float* cb0 = c_hist + cblk + (size_t)cb * HSL + jd;
    cg0 = *(const float2*)(cb0 + (size_t)ist2[slot][cb * 3]     * (NB * HSL));
    cg1 = *(const float2*)(cb0 + (size_t)ist2[slot][cb * 3 + 1] * (NB * HSL));
    cg2 = *(const float2*)(cb0 + (size_t)ist2[slot][cb * 3 + 2] * (NB * HSL));
    const unsigned short* gxr = gx + ((size_t)tn * BB + bg) * G4 + g * HSL + jd;
    gxv0 = *(const unsigned*)(gxr);
    gxv1 = *(const unsigned*)(gxr + 512);
    gxv2 = *(const unsigned*)(gxr + 1024);
    gxv3 = *(const unsigned*)(gxr + 1536);
  };

  // ---------------- t = 0 prologue ----------------
  {
    const unsigned short* gxr = gx + (size_t)bg * G4 + g * HSL + jd;
    gxv0 = *(const unsigned*)(gxr);
    gxv1 = *(const unsigned*)(gxr + 512);
    gxv2 = *(const unsigned*)(gxr + 1024);
    gxv3 = *(const unsigned*)(gxr + 1536);
    if (tid < NB * 3){
      int b = tid / 3, k = tid - b * 3;
      ist2[1][tid] = prev_idx[(size_t)(grp * NB + b) * (SS * KKK) + 1 * KKK + k];
      wst2[1][tid] = prev_w [(size_t)(grp * NB + b) * (SS * KKK) + 1 * KKK + k];
    }
    float cn0 = sigm(blo(gxv0)) * tanh_(blo(gxv2));
    float cn1 = sigm(bhi(gxv0)) * tanh_(bhi(gxv2));
    float hn0 = sigm(blo(gxv3)) * tanh_(cn0);
    float hn1 = sigm(bhi(gxv3)) * tanh_(cn1);
    *(float2*)(c_hist + cblk + (size_t)cb * HSL + jd) = make_float2(cn0, cn1);
    unsigned long long hv = ((unsigned long long)1u << 32)
                          | (unsigned long long)(f2bf(hn0) | (f2bf(hn1) << 16));
    __hip_atomic_store(h_hist + (((size_t)grp * GS + g) * NB + cb) * 32 + (jd >> 1), hv,
                       __ATOMIC_RELAXED, __HIP_MEMORY_SCOPE_AGENT);
    if (0 >= st && 0 < en){ pm0 = fmaxf(pm0, hn0); pm1 = fmaxf(pm1, hn1); }
    __syncthreads();   // full drain: c visible, ist2[1]/wst2[1] published
    issue_gather(1);   // unconditional; stamps self-validate at t=1
    issue_cgx(1, 1);
  }

  // ---------------- main loop ----------------
  for (int t = 1; t < SS; t++){
    const int sl = t & 1, sn = sl ^ 1;

    // [B] pack optimistically, validate stamps, retry until block-wide ok
    {
      bool ok = check_stamps(sl);
      while (!__syncthreads_and(ok)){
        if (!ok){
          issue_gather(sl);
          ok = check_stamps(sl);
        }
      }
      float w0 = wst2[sl][gq * 3], w1 = wst2[sl][gq * 3 + 1], w2 = wst2[sl][gq * 3 + 2];
      unsigned pk[8];
      #pragma unroll
      for (int j = 0; j < 8; j++){
        unsigned d0 = (unsigned)dq0[j], d1 = (unsigned)dq1[j], d2 = (unsigned)dq2[j];
        float lo = w0 * blo(d0) + w1 * blo(d1) + w2 * blo(d2);
        float hi = w0 * bhi(d0) + w1 * bhi(d1) + w2 * bhi(d2);
        pk[j] = f2bf(lo) | (f2bf(hi) << 16);
      }
      int ob = (gq << 10) + gd * 32;
      int xr = (gq & 7) << 4;
      *(uint4*)(hA + (ob ^ xr))        = (uint4){pk[0], pk[1], pk[2], pk[3]};
      *(uint4*)(hA + ((ob + 16) ^ xr)) = (uint4){pk[4], pk[5], pk[6], pk[7]};
    }
    __syncthreads();

    // [C] ist/wst(t+1) load (overlaps MFMA) + MFMA: wave w -> gate cols [32w,32w+32)
    if (t + 1 < SS && tid < NB * 3){
      int b = tid / 3, k = tid - b * 3;
      ist2[sn][tid] = prev_idx[(size_t)(grp * NB + b) * (SS * KKK) + (t + 1) * KKK + k];
      wst2[sn][tid] = prev_w [(size_t)(grp * NB + b) * (SS * KKK) + (t + 1) * KKK + k];
    }
    {
      f32x4 p00 = {0,0,0,0}, p01 = {0,0,0,0}, p10 = {0,0,0,0}, p11 = {0,0,0,0};
      const int rA = lane & 15;
      const int kb = (lane >> 4) << 4;
      const int xr = (rA & 7) << 4;
      const int rbase = rA << 10;
      #pragma unroll
      for (int kf = 0; kf < 16; kf += 2){
        bf16x8 a0 = *(const bf16x8*)(hA + ((rbase + kf * 64 + kb) ^ xr));
        bf16x8 a1 = *(const bf16x8*)(hA + ((rbase + (kf + 1) * 64 + kb) ^ xr));
        p00 = __builtin_amdgcn_mfma_f32_16x16x32_bf16(a0, bfr0[kf],     p00, 0, 0, 0);
        p10 = __builtin_amdgcn_mfma_f32_16x16x32_bf16(a0, bfr1[kf],     p10, 0, 0, 0);
        p01 = __builtin_amdgcn_mfma_f32_16x16x32_bf16(a1, bfr0[kf + 1], p01, 0, 0, 0);
        p11 = __builtin_amdgcn_mfma_f32_16x16x32_bf16(a1, bfr1[kf + 1], p11, 0, 0, 0);
      }
      int cl0 = (2 * w) * 16 + rA, cl1 = cl0 + 16;
      #pragma unroll
      for (int j = 0; j < 4; j++){
        int bq = ((lane >> 4) << 2) + j;
        gex[bq][cl0] = p00[j] + p01[j];
        gex[bq][cl1] = p10[j] + p11[j];
      }
    }
    __syncthreads();

    // [D] elementwise LSTM cell -> c store -> stamped h store
    {
      float w0 = wst2[sl][cb * 3], w1 = wst2[sl][cb * 3 + 1], w2 = wst2[sl][cb * 3 + 2];
      float g_i0 = blo(gxv0) + gex[cb][jd];
      float g_i1 = bhi(gxv0) + gex[cb][jd + 1];
      float g_f0 = blo(gxv1) + gex[cb][64 + jd];
      float g_f1 = bhi(gxv1) + gex[cb][64 + jd + 1];
      float g_g0 = blo(gxv2) + gex[cb][128 + jd];
      float g_g1 = bhi(gxv2) + gex[cb][128 + jd + 1];
      float g_o0 = blo(gxv3) + gex[cb][192 + jd];
      float g_o1 = bhi(gxv3) + gex[cb][192 + jd + 1];
      float co0 = w0 * cg0.x + w1 * cg1.x + w2 * cg2.x;
      float co1 = w0 * cg0.y + w1 * cg1.y + w2 * cg2.y;
      float cn0 = sigm(g_f0) * co0 + sigm(g_i0) * tanh_(g_g0);
      float cn1 = sigm(g_f1) * co1 + sigm(g_i1) * tanh_(g_g1);
      float hn0 = sigm(g_o0) * tanh_(cn0);
      float hn1 = sigm(g_o1) * tanh_(cn1);
      *(float2*)(c_hist + cblk + ((size_t)t * NB + cb) * HSL + jd) = make_float2(cn0, cn1);
      unsigned long long hv = ((unsigned long long)(unsigned)(t + 1) << 32)
                            | (unsigned long long)(f2bf(hn0) | (f2bf(hn1) << 16));
      __hip_atomic_store(h_hist + ((((size_t)t * NG + grp) * GS + g) * NB + cb) * 32 + (jd >> 1),
                         hv, __ATOMIC_RELAXED, __HIP_MEMORY_SCOPE_AGENT);
      if (t >= st && t < en){ pm0 = fmaxf(pm0, hn0); pm1 = fmaxf(pm1, hn1); }
    }
    // pin: the 2 stores above must be issued before the gathers below
    asm volatile("" ::: "memory");
    __builtin_amdgcn_sched_barrier(0);

    // [E] unconditional h-gather prefetch for t+1 (24 loads), then counted drain:
    //     vmcnt(24) retires the 2 stores (oldest, in-order) while gathers fly.
    if (t + 1 < SS)
      issue_gather(sn);
    asm volatile("s_waitcnt vmcnt(24) lgkmcnt(0)\n\ts_barrier" ::: "memory");
    __builtin_amdgcn_sched_barrier(0);

    // post-barrier: c store drained -> own-block c/gx prefetch is safe
    if (t + 1 < SS)
      issue_cgx(sn, t + 1);
  }

  pooled[(size_t)bg * HH + g * HSL + jd]     = (en > st && pm0 > -1e29f) ? pm0 : 0.f;
  pooled[(size_t)bg * HH + g * HSL + jd + 1] = (en > st && pm1 > -1e29f) ? pm1 : 0.f;
}

// ---------------- pool_lin ----------------
__global__ __launch_bounds__(128) void pool_lin(
    const float* __restrict__ pooled, const float* __restrict__ W_lin,
    const float* __restrict__ b_lin, float* __restrict__ out)
{
  __shared__ float p[HH];
  int b = blockIdx.x, tid = threadIdx.x;
  *(float4*)&p[tid * 4] = *(const float4*)&pooled[(size_t)b * HH + tid * 4];
  __syncthreads();
  float acc = b_lin[tid];
  const float* wr = W_lin + (size_t)tid * HH;
  #pragma unroll 8
  for (int h = 0; h < HH; h += 4){
    float4 w = *(const float4*)(wr + h);
    acc += w.x * p[h] + w.y * p[h+1] + w.z * p[h+2] + w.w * p[h+3];
  }
  out[b * LL + tid] = acc;
}

extern "C" void kernel_launch(void* const* d_in, const int* in_sizes, int n_in,
                              void* d_out, int out_size, void* d_ws, size_t ws_size,
                              hipStream_t stream)
{
  (void)in_sizes; (void)n_in; (void)out_size; (void)ws_size;
  const int*   inputs    = (const int*)  d_in[0];
  const int*   positions = (const int*)  d_in[1];
  const int*   prev_idx  = (const int*)  d_in[2];
  const float* prev_w    = (const float*)d_in[3];
  const float* emb       = (const float*)d_in[4];
  const float* Wih       = (const float*)d_in[5];
  const float* Whh       = (const float*)d_in[6];
  const float* bih       = (const float*)d_in[7];
  const float* bhh       = (const float*)d_in[8];
  const float* W_lin     = (const float*)d_in[9];
  const float* b_lin     = (const float*)d_in[10];
  float* out = (float*)d_out;
  char* ws = (char*)d_ws;

  // Layout (64.1 MB total; c_hist overlays dead prep buffers):
  //   [4096, 8392704)      Xb    8 MB   (dead after gemm_gx)
  //   [8392704, 10489856)  Wihb  2 MB   (dead after gemm_gx)
  //   [10489856, 10498048) bias  8 KB   (dead after gemm_gx)
  //   [4096, 16781312)     c_hist 16 MB (recur only; overlays the above)
  //   [16781312, 50335744) gx    32 MB
  //   [50335744, 67112960) h_hist 16 MB (stamped u64 pairs; memset 0)
  //   [67112960, 67178496) pooled 64 KB
  unsigned short*     Xb     = (unsigned short*)    (ws + 4096);
  unsigned short*     Wihb   = (unsigned short*)    (ws + 8392704);
  float*              bias   = (float*)             (ws + 10489856);
  float*              c_hist = (float*)             (ws + 4096);
  unsigned short*     gx     = (unsigned short*)    (ws + 16781312);
  unsigned long long* h_hist = (unsigned long long*)(ws + 50335744);
  float*              pooled = (float*)             (ws + 67112960);

  hipMemsetAsync(h_hist, 0, 16777216, stream);
  prep_kernel<<<641, 256, 0, stream>>>(inputs, emb, Wih, bih, bhh, Xb, Wihb, bias);
  gemm_gx<<<dim3(64, 16), 256, 0, stream>>>(Xb, Wihb, bias, gx);
  recur11<<<16, 512, 0, stream>>>(prev_idx, prev_w, Whh, positions, gx, h_hist, c_hist, pooled);
  pool_lin<<<32, 128, 0, stream>>>(pooled, W_lin, b_lin, out);
}

// Round 12
// 1516.481 us; speedup vs baseline: 2.8549x; 2.8549x over previous
//
#include <hip/hip_runtime.h>

// SLULatticeRNN: B=32, S=256, K=3, D=H=512, 4H=2048, L=128.
// recur12 = recur9 (PASSED, 1459us, best) + ONE isolated delta re-tested from
// r10 without its confound: validated gather issued AFTER [D]'s stores, then
//   valid:   s_waitcnt vmcnt(12); s_barrier  (retires the 2 stores in-order,
//            leaves the 12 gather loads in flight across the barrier)
//   invalid: s_waitcnt vmcnt(0);  s_barrier
// Tag snapshot stays block-level in LDS (r9 scheme, no per-wave replication).
// Memory semantics unchanged (proven r2/r5/r8/r9): relaxed agent atomics for
// h_hist + tags; plain cached for block-private c_hist and read-only gx.

#define BB 32
#define SS 256
#define KKK 3
#define DD 512
#define HH 512
#define G4 2048
#define LL 128
#define NG 2    // batch groups
#define GS 8    // slice blocks per group
#define NB 16   // batches per group
#define HSL 64  // h dims per slice block

typedef __attribute__((ext_vector_type(4))) float f32x4;
typedef __attribute__((ext_vector_type(8))) short bf16x8;

__device__ __forceinline__ float blo(unsigned u){ return __builtin_bit_cast(float, u << 16); }
__device__ __forceinline__ float bhi(unsigned u){ return __builtin_bit_cast(float, u & 0xffff0000u); }
__device__ __forceinline__ unsigned f2bf(float f){
  unsigned x = __builtin_bit_cast(unsigned, f);
  x = x + 0x7fffu + ((x >> 16) & 1u);
  return x >> 16;
}
__device__ __forceinline__ float sigm(float x){ return 1.0f / (1.0f + __expf(-x)); }
__device__ __forceinline__ float tanh_(float x){
  float ax = fabsf(x);
  float e = __expf(-2.0f * ax);
  float r = (1.0f - e) / (1.0f + e);
  return x < 0.0f ? -r : r;
}
__device__ __forceinline__ void glds16(const void* g, void* lds){
  __builtin_amdgcn_global_load_lds((const __attribute__((address_space(1))) unsigned int*)g,
                                   (__attribute__((address_space(3))) unsigned int*)lds, 16, 0, 0);
}

// ---------------- prep: X gather->bf16, Wih->bf16, bias ----------------
__global__ __launch_bounds__(256) void prep_kernel(
    const int* __restrict__ inputs, const float* __restrict__ emb,
    const float* __restrict__ Wih, const float* __restrict__ bih, const float* __restrict__ bhh,
    unsigned short* __restrict__ Xb, unsigned short* __restrict__ Wihb, float* __restrict__ bias)
{
  int blk = blockIdx.x, tid = threadIdx.x;
  if (blk < 512){
    int row = blk * 16 + (tid >> 4);       // m = t*32+b
    int d0 = (tid & 15) * 32;
    int b = row & 31, t = row >> 5;
    int tok = inputs[b * SS + t];
    const float* src = emb + (size_t)tok * DD + d0;
    unsigned short* dst = Xb + (size_t)row * DD + d0;
    #pragma unroll
    for (int j = 0; j < 32; j += 4){
      float4 v = *(const float4*)(src + j);
      uint2 o;
      o.x = f2bf(v.x) | (f2bf(v.y) << 16);
      o.y = f2bf(v.z) | (f2bf(v.w) << 16);
      *(uint2*)(dst + j) = o;
    }
  } else if (blk < 640){
    int row = (blk - 512) * 16 + (tid >> 4);
    int d0 = (tid & 15) * 32;
    const float* src = Wih + (size_t)row * DD + d0;
    unsigned short* dst = Wihb + (size_t)row * DD + d0;
    #pragma unroll
    for (int j = 0; j < 32; j += 4){
      float4 v = *(const float4*)(src + j);
      uint2 o;
      o.x = f2bf(v.x) | (f2bf(v.y) << 16);
      o.y = f2bf(v.z) | (f2bf(v.w) << 16);
      *(uint2*)(dst + j) = o;
    }
  } else {
    for (int n = tid; n < G4; n += 256) bias[n] = bih[n] + bhh[n];
  }
}

// ---------------- gemm_gx: gates_x[m][n] = X[m]·Wih[n] + bias[n], bf16 out ----------------
__global__ __launch_bounds__(256) void gemm_gx(
    const unsigned short* __restrict__ Xb, const unsigned short* __restrict__ Wihb,
    const float* __restrict__ bias, unsigned short* __restrict__ gx)
{
  __shared__ unsigned short As[128 * 32];
  __shared__ unsigned short Bs[128 * 32];
  const int tid = threadIdx.x;
  const int lane = tid & 63, wid = tid >> 6;
  const int m0 = blockIdx.x * 128, n0 = blockIdx.y * 128;
  const int wm = wid & 1, wn = wid >> 1;
  f32x4 acc[4][4];
  #pragma unroll
  for (int i = 0; i < 4; i++)
    #pragma unroll
    for (int j = 0; j < 4; j++)
      acc[i][j] = (f32x4){0.f, 0.f, 0.f, 0.f};

  for (int kk = 0; kk < DD; kk += 32){
    #pragma unroll
    for (int r = 0; r < 2; r++){
      int q = r * 256 + wid * 64 + lane;
      int row = q >> 2, seg = q & 3;
      glds16(Xb   + (size_t)(m0 + row) * DD + kk + seg * 8, As + (size_t)(r * 256 + wid * 64) * 8);
      glds16(Wihb + (size_t)(n0 + row) * DD + kk + seg * 8, Bs + (size_t)(r * 256 + wid * 64) * 8);
    }
    __syncthreads();
    bf16x8 af[4], bfv[4];
    #pragma unroll
    for (int i = 0; i < 4; i++){
      int ra = wm * 64 + i * 16 + (lane & 15);
      af[i] = *(const bf16x8*)(As + ra * 32 + (lane >> 4) * 8);
      int rb = wn * 64 + i * 16 + (lane & 15);
      bfv[i] = *(const bf16x8*)(Bs + rb * 32 + (lane >> 4) * 8);
    }
    #pragma unroll
    for (int i = 0; i < 4; i++)
      #pragma unroll
      for (int j = 0; j < 4; j++)
        acc[i][j] = __builtin_amdgcn_mfma_f32_16x16x32_bf16(af[i], bfv[j], acc[i][j], 0, 0, 0);
    __syncthreads();
  }
  #pragma unroll
  for (int j = 0; j < 4; j++){
    int ncol = n0 + wn * 64 + j * 16 + (lane & 15);
    float bv = bias[ncol];
    #pragma unroll
    for (int i = 0; i < 4; i++){
      int mbase = m0 + wm * 64 + i * 16 + (lane >> 4) * 4;
      #pragma unroll
      for (int r = 0; r < 4; r++)
        gx[(size_t)(mbase + r) * G4 + ncol] = (unsigned short)f2bf(acc[i][j][r] + bv);
    }
  }
}

// ---------------- recur12 ----------------
// grid = 16 x 512. grp = bid>>3 (16 batches), g = bid&7 (64-dim h slice).
// h_hist [SS][NG][GS][NB][HSL] bf16: relaxed agent atomics only.
// c_hist [16][SS][NB][HSL] f32: block-private, plain cached.
// tags[16]: monotonic published-step counters, relaxed agent atomics.
__global__ __launch_bounds__(512, 1) void recur12(
    const int* __restrict__ prev_idx, const float* __restrict__ prev_w,
    const float* __restrict__ Whh, const int* __restrict__ positions,
    const unsigned short* __restrict__ gx,
    unsigned short* __restrict__ h_hist, float* __restrict__ c_hist,
    float* __restrict__ pooled, unsigned int* __restrict__ tags)
{
  __shared__ __align__(16) unsigned char hA[16 * 1024];  // h~ [16b][512] bf16, XOR-swizzled
  __shared__ float gex[NB][264];
  __shared__ float wst2[2][NB * 3];
  __shared__ int   ist2[2][NB * 3];
  __shared__ int   wm_l[GS];          // cached lower bounds of peer tags
  __shared__ int   snap_l[GS];        // this step's tag snapshot (staged in [C])
  __shared__ int   mneed2[2];         // max prev_idx per step slot

  const int tid = threadIdx.x;
  const int lane = tid & 63, w = tid >> 6;
  const int bid = blockIdx.x, grp = bid >> 3, g = bid & 7;

  // ---- persistent B-fragments: Whh rows {q*512 + g*64 + [0,64)} ----
  bf16x8 bfr0[16], bfr1[16];
  #pragma unroll
  for (int kf = 0; kf < 16; kf++){
    #pragma unroll
    for (int i = 0; i < 2; i++){
      int nt = 2 * w + i;
      int grow = (nt >> 2) * HH + g * HSL + ((nt & 3) << 4) + (lane & 15);
      int kcol = kf * 32 + ((lane >> 4) << 3);
      const float* p = Whh + (size_t)grow * HH + kcol;
      float4 v0 = *(const float4*)p;
      float4 v1 = *(const float4*)(p + 4);
      bf16x8 tf;
      tf[0] = (short)f2bf(v0.x); tf[1] = (short)f2bf(v0.y);
      tf[2] = (short)f2bf(v0.z); tf[3] = (short)f2bf(v0.w);
      tf[4] = (short)f2bf(v1.x); tf[5] = (short)f2bf(v1.y);
      tf[6] = (short)f2bf(v1.z); tf[7] = (short)f2bf(v1.w);
      if (i == 0) bfr0[kf] = tf; else bfr1[kf] = tf;
    }
  }

  // mappings
  const int cb = tid >> 5;             // local batch (elementwise)
  const int jd = (tid & 31) << 1;      // dim pair within slice
  const int bg = grp * NB + cb;
  const int gq = tid & 15;             // batch (gather)
  const int gd = tid >> 4;             // 16-dim chunk of 512
  const int ggs = gd >> 2;             // peer slice
  const int gdof = (gd & 3) << 4;      // dim offset in slice

  const int st = positions[bg * 2], en = positions[bg * 2 + 1];
  float pm0 = -1e30f, pm1 = -1e30f;
  const size_t cblk = (size_t)bid * ((size_t)SS * NB * HSL);
  const unsigned long long* hq = (const unsigned long long*)h_hist;
  unsigned* hbw = (unsigned*)h_hist;

  // prefetch registers (statically indexed)
  unsigned long long dq0[4], dq1[4], dq2[4];
  float2 cg0, cg1, cg2;
  unsigned gxv0, gxv1, gxv2, gxv3;

  if (tid < GS){ wm_l[tid] = 0; snap_l[tid] = 0; }
  __syncthreads();

  auto issue_gather = [&](int slot){
    int i0 = ist2[slot][gq * 3], i1 = ist2[slot][gq * 3 + 1], i2 = ist2[slot][gq * 3 + 2];
    size_t s0 = (((((size_t)i0 * NG + grp) * GS + ggs) * NB + gq) * HSL + gdof) >> 2;
    size_t s1 = (((((size_t)i1 * NG + grp) * GS + ggs) * NB + gq) * HSL + gdof) >> 2;
    size_t s2 = (((((size_t)i2 * NG + grp) * GS + ggs) * NB + gq) * HSL + gdof) >> 2;
    #pragma unroll
    for (int j = 0; j < 4; j++)
      dq0[j] = __hip_atomic_load(hq + s0 + j, __ATOMIC_RELAXED, __HIP_MEMORY_SCOPE_AGENT);
    #pragma unroll
    for (int j = 0; j < 4; j++)
      dq1[j] = __hip_atomic_load(hq + s1 + j, __ATOMIC_RELAXED, __HIP_MEMORY_SCOPE_AGENT);
    #pragma unroll
    for (int j = 0; j < 4; j++)
      dq2[j] = __hip_atomic_load(hq + s2 + j, __ATOMIC_RELAXED, __HIP_MEMORY_SCOPE_AGENT);
  };
  auto issue_cgx = [&](int slot, int tn){
    const float* cb0 = c_hist + cblk + (size_t)cb * HSL + jd;
    cg0 = *(const float2*)(cb0 + (size_t)ist2[slot][cb * 3]     * (NB * HSL));
    cg1 = *(const float2*)(cb0 + (size_t)ist2[slot][cb * 3 + 1] * (NB * HSL));
    cg2 = *(const float2*)(cb0 + (size_t)ist2[slot][cb * 3 + 2] * (NB * HSL));
    const unsigned short* gxr = gx + ((size_t)tn * BB + bg) * G4 + g * HSL + jd;
    gxv0 = *(const unsigned*)(gxr);
    gxv1 = *(const unsigned*)(gxr + 512);
    gxv2 = *(const unsigned*)(gxr + 1024);
    gxv3 = *(const unsigned*)(gxr + 1536);
  };

  // ---------------- t = 0 prologue ----------------
  {
    const unsigned short* gxr = gx + (size_t)bg * G4 + g * HSL + jd;
    gxv0 = *(const unsigned*)(gxr);
    gxv1 = *(const unsigned*)(gxr + 512);
    gxv2 = *(const unsigned*)(gxr + 1024);
    gxv3 = *(const unsigned*)(gxr + 1536);
    int iv = -1;
    if (tid < NB * 3){
      int b = tid / 3, k = tid - b * 3;
      iv = prev_idx[(size_t)(grp * NB + b) * (SS * KKK) + 1 * KKK + k];
      ist2[1][tid] = iv;
      wst2[1][tid] = prev_w[(size_t)(grp * NB + b) * (SS * KKK) + 1 * KKK + k];
    }
    if (tid < 64){
      int m = iv;
      #pragma unroll
      for (int off = 32; off; off >>= 1) m = max(m, __shfl_xor(m, off));
      if (tid == 0) mneed2[1] = m;
    }
    float cn0 = sigm(blo(gxv0)) * tanh_(blo(gxv2));
    float cn1 = sigm(bhi(gxv0)) * tanh_(bhi(gxv2));
    float hn0 = sigm(blo(gxv3)) * tanh_(cn0);
    float hn1 = sigm(bhi(gxv3)) * tanh_(cn1);
    *(float2*)(c_hist + cblk + (size_t)cb * HSL + jd) = make_float2(cn0, cn1);
    unsigned hv = f2bf(hn0) | (f2bf(hn1) << 16);
    __hip_atomic_store(hbw + (((((size_t)grp * GS + g) * NB + cb) * HSL + jd) >> 1), hv,
                       __ATOMIC_RELAXED, __HIP_MEMORY_SCOPE_AGENT);
    if (0 >= st && 0 < en){ pm0 = fmaxf(pm0, hn0); pm1 = fmaxf(pm1, hn1); }
    __syncthreads();   // drains h/c stores; publishes ist2[1]/mneed2[1] block-wide
    if (tid == 0){
      __hip_atomic_store(&tags[grp * GS + g], 1u, __ATOMIC_RELAXED, __HIP_MEMORY_SCOPE_AGENT);
      wm_l[g] = 1;
    }
    issue_cgx(1, 1);
  }
  bool valid = false;   // first-step gather always via fallback

  // ---------------- main loop ----------------
  for (int t = 1; t < SS; t++){
    const int sl = t & 1, sn = sl ^ 1;

    // [S] pipelined tag snapshot: issue now, staged to snap_l in [C]
    unsigned tsnap = 0;
    if (tid < GS)
      tsnap = __hip_atomic_load(&tags[grp * GS + tid], __ATOMIC_RELAXED,
                                __HIP_MEMORY_SCOPE_AGENT);

    // [A] blocking poll only when prefetch wasn't validated (true fresh deps);
    //     own tag always covers need (<= t), so skip tid == g
    if (!valid){
      const int need = mneed2[sl] + 1;
      if (tid < GS && tid != g){
        int v = wm_l[tid];
        if (v < need){
          const unsigned int* tp = tags + grp * GS + tid;
          do {
            v = (int)__hip_atomic_load(tp, __ATOMIC_RELAXED, __HIP_MEMORY_SCOPE_AGENT);
            if (v < need) __builtin_amdgcn_s_sleep(1);
          } while (v < need);
          wm_l[tid] = v;
        }
      }
      __syncthreads();
      issue_gather(sl);
    }

    // [B] weight + pack h~ -> hA (XOR-swizzled)
    {
      float w0 = wst2[sl][gq * 3], w1 = wst2[sl][gq * 3 + 1], w2 = wst2[sl][gq * 3 + 2];
      unsigned pk[8];
      #pragma unroll
      for (int j = 0; j < 4; j++){
        unsigned a_lo = (unsigned)dq0[j], a_hi = (unsigned)(dq0[j] >> 32);
        unsigned b_lo = (unsigned)dq1[j], b_hi = (unsigned)(dq1[j] >> 32);
        unsigned c_lo = (unsigned)dq2[j], c_hi = (unsigned)(dq2[j] >> 32);
        float l0 = w0 * blo(a_lo) + w1 * blo(b_lo) + w2 * blo(c_lo);
        float h0 = w0 * bhi(a_lo) + w1 * bhi(b_lo) + w2 * bhi(c_lo);
        float l1 = w0 * blo(a_hi) + w1 * blo(b_hi) + w2 * blo(c_hi);
        float h1 = w0 * bhi(a_hi) + w1 * bhi(b_hi) + w2 * bhi(c_hi);
        pk[2 * j]     = f2bf(l0) | (f2bf(h0) << 16);
        pk[2 * j + 1] = f2bf(l1) | (f2bf(h1) << 16);
      }
      int ob = (gq << 10) + gd * 32;
      int xr = (gq & 7) << 4;
      *(uint4*)(hA + (ob ^ xr))        = (uint4){pk[0], pk[1], pk[2], pk[3]};
      *(uint4*)(hA + ((ob + 16) ^ xr)) = (uint4){pk[4], pk[5], pk[6], pk[7]};
    }
    __syncthreads();

    // [C] ist/wst(t+1) load + MFMA + snapshot staging
    int iv = -1;
    if (t + 1 < SS){
      if (tid < NB * 3){
        int b = tid / 3, k = tid - b * 3;
        iv = prev_idx[(size_t)(grp * NB + b) * (SS * KKK) + (t + 1) * KKK + k];
        ist2[sn][tid] = iv;
        wst2[sn][tid] = prev_w[(size_t)(grp * NB + b) * (SS * KKK) + (t + 1) * KKK + k];
      }
    }
    {
      f32x4 p00 = {0,0,0,0}, p01 = {0,0,0,0}, p10 = {0,0,0,0}, p11 = {0,0,0,0};
      const int rA = lane & 15;
      const int kb = (lane >> 4) << 4;
      const int xr = (rA & 7) << 4;
      const int rbase = rA << 10;
      #pragma unroll
      for (int kf = 0; kf < 16; kf += 2){
        bf16x8 a0 = *(const bf16x8*)(hA + ((rbase + kf * 64 + kb) ^ xr));
        bf16x8 a1 = *(const bf16x8*)(hA + ((rbase + (kf + 1) * 64 + kb) ^ xr));
        p00 = __builtin_amdgcn_mfma_f32_16x16x32_bf16(a0, bfr0[kf],     p00, 0, 0, 0);
        p10 = __builtin_amdgcn_mfma_f32_16x16x32_bf16(a0, bfr1[kf],     p10, 0, 0, 0);
        p01 = __builtin_amdgcn_mfma_f32_16x16x32_bf16(a1, bfr0[kf + 1], p01, 0, 0, 0);
        p11 = __builtin_amdgcn_mfma_f32_16x16x32_bf16(a1, bfr1[kf + 1], p11, 0, 0, 0);
      }
      int cl0 = (2 * w) * 16 + rA, cl1 = cl0 + 16;
      #pragma unroll
      for (int j = 0; j < 4; j++){
        int bq = ((lane >> 4) << 2) + j;
        gex[bq][cl0] = p00[j] + p01[j];
        gex[bq][cl1] = p10[j] + p11[j];
      }
    }
    if (t + 1 < SS && tid < 64){
      int m = iv;
      #pragma unroll
      for (int off = 32; off; off >>= 1) m = max(m, __shfl_xor(m, off));
      if (tid == 0) mneed2[sn] = m;
    }
    if (tid < GS) snap_l[tid] = (int)tsnap;
    __syncthreads();

    // [D] elementwise LSTM cell (gex LDS + prefetched gx/c regs) + stores
    {
      float w0 = wst2[sl][cb * 3], w1 = wst2[sl][cb * 3 + 1], w2 = wst2[sl][cb * 3 + 2];
      float g_i0 = blo(gxv0) + gex[cb][jd];
      float g_i1 = bhi(gxv0) + gex[cb][jd + 1];
      float g_f0 = blo(gxv1) + gex[cb][64 + jd];
      float g_f1 = bhi(gxv1) + gex[cb][64 + jd + 1];
      float g_g0 = blo(gxv2) + gex[cb][128 + jd];
      float g_g1 = bhi(gxv2) + gex[cb][128 + jd + 1];
      float g_o0 = blo(gxv3) + gex[cb][192 + jd];
      float g_o1 = bhi(gxv3) + gex[cb][192 + jd + 1];
      float co0 = w0 * cg0.x + w1 * cg1.x + w2 * cg2.x;
      float co1 = w0 * cg0.y + w1 * cg1.y + w2 * cg2.y;
      float cn0 = sigm(g_f0) * co0 + sigm(g_i0) * tanh_(g_g0);
      float cn1 = sigm(g_f1) * co1 + sigm(g_i1) * tanh_(g_g1);
      float hn0 = sigm(g_o0) * tanh_(cn0);
      float hn1 = sigm(g_o1) * tanh_(cn1);
      *(float2*)(c_hist + cblk + ((size_t)t * NB + cb) * HSL + jd) = make_float2(cn0, cn1);
      unsigned hv = f2bf(hn0) | (f2bf(hn1) << 16);
      __hip_atomic_store(hbw + ((((((size_t)t * NG + grp) * GS + g) * NB + cb) * HSL + jd) >> 1),
                         hv, __ATOMIC_RELAXED, __HIP_MEMORY_SCOPE_AGENT);
      if (t >= st && t < en){ pm0 = fmaxf(pm0, hn0); pm1 = fmaxf(pm1, hn1); }
    }
    // pin: the 2 stores above must be issued before any gather loads below
    asm volatile("" ::: "memory");
    __builtin_amdgcn_sched_barrier(0);

    // [V] fold snapshot + validate (benign race as in r9: max(wm,snap) idempotent),
    //     then EARLY validated gather issue AFTER the stores -> counted drain:
    //     outstanding = 2 stores + 12 gathers; vmcnt(12) retires exactly the stores.
    if (tid < GS) wm_l[tid] = max(wm_l[tid], snap_l[tid]);
    bool validn = false;
    if (t + 1 < SS){
      const int need = mneed2[sn] + 1;
      int m = max(wm_l[0], snap_l[0]);
      #pragma unroll
      for (int p = 1; p < GS; p++) m = min(m, max(wm_l[p], snap_l[p]));
      validn = (m >= need);
    }
    if (validn){
      issue_gather(sn);
      asm volatile("s_waitcnt vmcnt(12) lgkmcnt(0)\n\ts_barrier" ::: "memory");
      __builtin_amdgcn_sched_barrier(0);
    } else {
      asm volatile("s_waitcnt vmcnt(0) lgkmcnt(0)\n\ts_barrier" ::: "memory");
      __builtin_amdgcn_sched_barrier(0);
    }

    // [E] publish + own-block prefetch for t+1
    if (tid == 0){
      __hip_atomic_store(&tags[grp * GS + g], (unsigned)(t + 1),
                         __ATOMIC_RELAXED, __HIP_MEMORY_SCOPE_AGENT);
      wm_l[g] = t + 1;
    }
    if (t + 1 < SS)
      issue_cgx(sn, t + 1);          // own-block data: always safe
    valid = validn;
  }

  pooled[(size_t)bg * HH + g * HSL + jd]     = (en > st && pm0 > -1e29f) ? pm0 : 0.f;
  pooled[(size_t)bg * HH + g * HSL + jd + 1] = (en > st && pm1 > -1e29f) ? pm1 : 0.f;
}

// ---------------- pool_lin ----------------
__global__ __launch_bounds__(128) void pool_lin(
    const float* __restrict__ pooled, const float* __restrict__ W_lin,
    const float* __restrict__ b_lin, float* __restrict__ out)
{
  __shared__ float p[HH];
  int b = blockIdx.x, tid = threadIdx.x;
  *(float4*)&p[tid * 4] = *(const float4*)&pooled[(size_t)b * HH + tid * 4];
  __syncthreads();
  float acc = b_lin[tid];
  const float* wr = W_lin + (size_t)tid * HH;
  #pragma unroll 8
  for (int h = 0; h < HH; h += 4){
    float4 w = *(const float4*)(wr + h);
    acc += w.x * p[h] + w.y * p[h+1] + w.z * p[h+2] + w.w * p[h+3];
  }
  out[b * LL + tid] = acc;
}

extern "C" void kernel_launch(void* const* d_in, const int* in_sizes, int n_in,
                              void* d_out, int out_size, void* d_ws, size_t ws_size,
                              hipStream_t stream)
{
  (void)in_sizes; (void)n_in; (void)out_size; (void)ws_size;
  const int*   inputs    = (const int*)  d_in[0];
  const int*   positions = (const int*)  d_in[1];
  const int*   prev_idx  = (const int*)  d_in[2];
  const float* prev_w    = (const float*)d_in[3];
  const float* emb       = (const float*)d_in[4];
  const float* Wih       = (const float*)d_in[5];
  const float* Whh       = (const float*)d_in[6];
  const float* bih       = (const float*)d_in[7];
  const float* bhh       = (const float*)d_in[8];
  const float* W_lin     = (const float*)d_in[9];
  const float* b_lin     = (const float*)d_in[10];
  float* out = (float*)d_out;
  char* ws = (char*)d_ws;

  unsigned int*   tags   = (unsigned int*)  ws;                 // 64 B
  unsigned short* Xb     = (unsigned short*)(ws + 4096);        // 8 MB
  unsigned short* Wihb   = (unsigned short*)(ws + 8392704);     // 2 MB
  float*          bias   = (float*)         (ws + 10489856);    // 8 KB
  unsigned short* gx     = (unsigned short*)(ws + 10498048);    // 32 MB
  unsigned short* h_hist = (unsigned short*)(ws + 44052480);    // 8 MB  [S][NG][GS][NB][HSL]
  float*          c_hist = (float*)         (ws + 52441088);    // 16 MB [16][S][NB][HSL]
  float*          pooled = (float*)         (ws + 69218304);    // 64 KB

  hipMemsetAsync(tags, 0, 4096, stream);
  prep_kernel<<<641, 256, 0, stream>>>(inputs, emb, Wih, bih, bhh, Xb, Wihb, bias);
  gemm_gx<<<dim3(64, 16), 256, 0, stream>>>(Xb, Wihb, bias, gx);
  recur12<<<16, 512, 0, stream>>>(prev_idx, prev_w, Whh, positions, gx, h_hist, c_hist, pooled, tags);
  pool_lin<<<32, 128, 0, stream>>>(pooled, W_lin, b_lin, out);
}

// Round 13
// 1450.729 us; speedup vs baseline: 2.9843x; 1.0453x over previous
//
#include <hip/hip_runtime.h>

// SLULatticeRNN: B=32, S=256, K=3, D=H=512, 4H=2048, L=128.
// FINAL = recur9 (best: 1459us, passed). Schedule-permutation family
// {r8,r9,r10,r12} = {1476,1459,1544,1516} -> floor is the lattice's
// binding-dependency chain through the MALL (proven-semantics coherence
// point), not the schedule. Reverted exactly to r9.
//   - relaxed agent atomics for h_hist + tags (proven r2/r5/r8/r9)
//   - continuous pipelined tag snapshot (issue at loop top, stage in [C],
//     fold+validate at [V]) -> blocking poll only on true fresh deps
//   - validated gather issued at [V] (hidden under [D]); fallback poll
//     skips own tag; 2 barriers/step
//   - block-private c_hist, read-only gx on the normal cached path

#define BB 32
#define SS 256
#define KKK 3
#define DD 512
#define HH 512
#define G4 2048
#define LL 128
#define NG 2    // batch groups
#define GS 8    // slice blocks per group
#define NB 16   // batches per group
#define HSL 64  // h dims per slice block

typedef __attribute__((ext_vector_type(4))) float f32x4;
typedef __attribute__((ext_vector_type(8))) short bf16x8;

__device__ __forceinline__ float blo(unsigned u){ return __builtin_bit_cast(float, u << 16); }
__device__ __forceinline__ float bhi(unsigned u){ return __builtin_bit_cast(float, u & 0xffff0000u); }
__device__ __forceinline__ unsigned f2bf(float f){
  unsigned x = __builtin_bit_cast(unsigned, f);
  x = x + 0x7fffu + ((x >> 16) & 1u);
  return x >> 16;
}
__device__ __forceinline__ float sigm(float x){ return 1.0f / (1.0f + __expf(-x)); }
__device__ __forceinline__ float tanh_(float x){
  float ax = fabsf(x);
  float e = __expf(-2.0f * ax);
  float r = (1.0f - e) / (1.0f + e);
  return x < 0.0f ? -r : r;
}
__device__ __forceinline__ void glds16(const void* g, void* lds){
  __builtin_amdgcn_global_load_lds((const __attribute__((address_space(1))) unsigned int*)g,
                                   (__attribute__((address_space(3))) unsigned int*)lds, 16, 0, 0);
}

// ---------------- prep: X gather->bf16, Wih->bf16, bias ----------------
__global__ __launch_bounds__(256) void prep_kernel(
    const int* __restrict__ inputs, const float* __restrict__ emb,
    const float* __restrict__ Wih, const float* __restrict__ bih, const float* __restrict__ bhh,
    unsigned short* __restrict__ Xb, unsigned short* __restrict__ Wihb, float* __restrict__ bias)
{
  int blk = blockIdx.x, tid = threadIdx.x;
  if (blk < 512){
    int row = blk * 16 + (tid >> 4);       // m = t*32+b
    int d0 = (tid & 15) * 32;
    int b = row & 31, t = row >> 5;
    int tok = inputs[b * SS + t];
    const float* src = emb + (size_t)tok * DD + d0;
    unsigned short* dst = Xb + (size_t)row * DD + d0;
    #pragma unroll
    for (int j = 0; j < 32; j += 4){
      float4 v = *(const float4*)(src + j);
      uint2 o;
      o.x = f2bf(v.x) | (f2bf(v.y) << 16);
      o.y = f2bf(v.z) | (f2bf(v.w) << 16);
      *(uint2*)(dst + j) = o;
    }
  } else if (blk < 640){
    int row = (blk - 512) * 16 + (tid >> 4);
    int d0 = (tid & 15) * 32;
    const float* src = Wih + (size_t)row * DD + d0;
    unsigned short* dst = Wihb + (size_t)row * DD + d0;
    #pragma unroll
    for (int j = 0; j < 32; j += 4){
      float4 v = *(const float4*)(src + j);
      uint2 o;
      o.x = f2bf(v.x) | (f2bf(v.y) << 16);
      o.y = f2bf(v.z) | (f2bf(v.w) << 16);
      *(uint2*)(dst + j) = o;
    }
  } else {
    for (int n = tid; n < G4; n += 256) bias[n] = bih[n] + bhh[n];
  }
}

// ---------------- gemm_gx: gates_x[m][n] = X[m]·Wih[n] + bias[n], bf16 out ----------------
__global__ __launch_bounds__(256) void gemm_gx(
    const unsigned short* __restrict__ Xb, const unsigned short* __restrict__ Wihb,
    const float* __restrict__ bias, unsigned short* __restrict__ gx)
{
  __shared__ unsigned short As[128 * 32];
  __shared__ unsigned short Bs[128 * 32];
  const int tid = threadIdx.x;
  const int lane = tid & 63, wid = tid >> 6;
  const int m0 = blockIdx.x * 128, n0 = blockIdx.y * 128;
  const int wm = wid & 1, wn = wid >> 1;
  f32x4 acc[4][4];
  #pragma unroll
  for (int i = 0; i < 4; i++)
    #pragma unroll
    for (int j = 0; j < 4; j++)
      acc[i][j] = (f32x4){0.f, 0.f, 0.f, 0.f};

  for (int kk = 0; kk < DD; kk += 32){
    #pragma unroll
    for (int r = 0; r < 2; r++){
      int q = r * 256 + wid * 64 + lane;
      int row = q >> 2, seg = q & 3;
      glds16(Xb   + (size_t)(m0 + row) * DD + kk + seg * 8, As + (size_t)(r * 256 + wid * 64) * 8);
      glds16(Wihb + (size_t)(n0 + row) * DD + kk + seg * 8, Bs + (size_t)(r * 256 + wid * 64) * 8);
    }
    __syncthreads();
    bf16x8 af[4], bfv[4];
    #pragma unroll
    for (int i = 0; i < 4; i++){
      int ra = wm * 64 + i * 16 + (lane & 15);
      af[i] = *(const bf16x8*)(As + ra * 32 + (lane >> 4) * 8);
      int rb = wn * 64 + i * 16 + (lane & 15);
      bfv[i] = *(const bf16x8*)(Bs + rb * 32 + (lane >> 4) * 8);
    }
    #pragma unroll
    for (int i = 0; i < 4; i++)
      #pragma unroll
      for (int j = 0; j < 4; j++)
        acc[i][j] = __builtin_amdgcn_mfma_f32_16x16x32_bf16(af[i], bfv[j], acc[i][j], 0, 0, 0);
    __syncthreads();
  }
  #pragma unroll
  for (int j = 0; j < 4; j++){
    int ncol = n0 + wn * 64 + j * 16 + (lane & 15);
    float bv = bias[ncol];
    #pragma unroll
    for (int i = 0; i < 4; i++){
      int mbase = m0 + wm * 64 + i * 16 + (lane >> 4) * 4;
      #pragma unroll
      for (int r = 0; r < 4; r++)
        gx[(size_t)(mbase + r) * G4 + ncol] = (unsigned short)f2bf(acc[i][j][r] + bv);
    }
  }
}

// ---------------- recur9 (final) ----------------
// grid = 16 x 512. grp = bid>>3 (16 batches), g = bid&7 (64-dim h slice).
// h_hist [SS][NG][GS][NB][HSL] bf16: relaxed agent atomics only.
// c_hist [16][SS][NB][HSL] f32: block-private, plain cached.
// tags[16]: monotonic published-step counters, relaxed agent atomics.
__global__ __launch_bounds__(512, 1) void recur9(
    const int* __restrict__ prev_idx, const float* __restrict__ prev_w,
    const float* __restrict__ Whh, const int* __restrict__ positions,
    const unsigned short* __restrict__ gx,
    unsigned short* __restrict__ h_hist, float* __restrict__ c_hist,
    float* __restrict__ pooled, unsigned int* __restrict__ tags)
{
  __shared__ __align__(16) unsigned char hA[16 * 1024];  // h~ [16b][512] bf16, XOR-swizzled
  __shared__ float gex[NB][264];
  __shared__ float wst2[2][NB * 3];
  __shared__ int   ist2[2][NB * 3];
  __shared__ int   wm_l[GS];          // cached lower bounds of peer tags
  __shared__ int   snap_l[GS];        // this step's tag snapshot (staged in [C])
  __shared__ int   mneed2[2];         // max prev_idx per step slot

  const int tid = threadIdx.x;
  const int lane = tid & 63, w = tid >> 6;
  const int bid = blockIdx.x, grp = bid >> 3, g = bid & 7;

  // ---- persistent B-fragments: Whh rows {q*512 + g*64 + [0,64)} ----
  bf16x8 bfr0[16], bfr1[16];
  #pragma unroll
  for (int kf = 0; kf < 16; kf++){
    #pragma unroll
    for (int i = 0; i < 2; i++){
      int nt = 2 * w + i;
      int grow = (nt >> 2) * HH + g * HSL + ((nt & 3) << 4) + (lane & 15);
      int kcol = kf * 32 + ((lane >> 4) << 3);
      const float* p = Whh + (size_t)grow * HH + kcol;
      float4 v0 = *(const float4*)p;
      float4 v1 = *(const float4*)(p + 4);
      bf16x8 tf;
      tf[0] = (short)f2bf(v0.x); tf[1] = (short)f2bf(v0.y);
      tf[2] = (short)f2bf(v0.z); tf[3] = (short)f2bf(v0.w);
      tf[4] = (short)f2bf(v1.x); tf[5] = (short)f2bf(v1.y);
      tf[6] = (short)f2bf(v1.z); tf[7] = (short)f2bf(v1.w);
      if (i == 0) bfr0[kf] = tf; else bfr1[kf] = tf;
    }
  }

  // mappings
  const int cb = tid >> 5;             // local batch (elementwise)
  const int jd = (tid & 31) << 1;      // dim pair within slice
  const int bg = grp * NB + cb;
  const int gq = tid & 15;             // batch (gather)
  const int gd = tid >> 4;             // 16-dim chunk of 512
  const int ggs = gd >> 2;             // peer slice
  const int gdof = (gd & 3) << 4;      // dim offset in slice

  const int st = positions[bg * 2], en = positions[bg * 2 + 1];
  float pm0 = -1e30f, pm1 = -1e30f;
  const size_t cblk = (size_t)bid * ((size_t)SS * NB * HSL);
  const unsigned long long* hq = (const unsigned long long*)h_hist;
  unsigned* hbw = (unsigned*)h_hist;

  // prefetch registers (statically indexed)
  unsigned long long dq0[4], dq1[4], dq2[4];
  float2 cg0, cg1, cg2;
  unsigned gxv0, gxv1, gxv2, gxv3;

  if (tid < GS){ wm_l[tid] = 0; snap_l[tid] = 0; }
  __syncthreads();

  auto issue_gather = [&](int slot){
    int i0 = ist2[slot][gq * 3], i1 = ist2[slot][gq * 3 + 1], i2 = ist2[slot][gq * 3 + 2];
    size_t s0 = (((((size_t)i0 * NG + grp) * GS + ggs) * NB + gq) * HSL + gdof) >> 2;
    size_t s1 = (((((size_t)i1 * NG + grp) * GS + ggs) * NB + gq) * HSL + gdof) >> 2;
    size_t s2 = (((((size_t)i2 * NG + grp) * GS + ggs) * NB + gq) * HSL + gdof) >> 2;
    #pragma unroll
    for (int j = 0; j < 4; j++)
      dq0[j] = __hip_atomic_load(hq + s0 + j, __ATOMIC_RELAXED, __HIP_MEMORY_SCOPE_AGENT);
    #pragma unroll
    for (int j = 0; j < 4; j++)
      dq1[j] = __hip_atomic_load(hq + s1 + j, __ATOMIC_RELAXED, __HIP_MEMORY_SCOPE_AGENT);
    #pragma unroll
    for (int j = 0; j < 4; j++)
      dq2[j] = __hip_atomic_load(hq + s2 + j, __ATOMIC_RELAXED, __HIP_MEMORY_SCOPE_AGENT);
  };
  auto issue_cgx = [&](int slot, int tn){
    const float* cb0 = c_hist + cblk + (size_t)cb * HSL + jd;
    cg0 = *(const float2*)(cb0 + (size_t)ist2[slot][cb * 3]     * (NB * HSL));
    cg1 = *(const float2*)(cb0 + (size_t)ist2[slot][cb * 3 + 1] * (NB * HSL));
    cg2 = *(const float2*)(cb0 + (size_t)ist2[slot][cb * 3 + 2] * (NB * HSL));
    const unsigned short* gxr = gx + ((size_t)tn * BB + bg) * G4 + g * HSL + jd;
    gxv0 = *(const unsigned*)(gxr);
    gxv1 = *(const unsigned*)(gxr + 512);
    gxv2 = *(const unsigned*)(gxr + 1024);
    gxv3 = *(const unsigned*)(gxr + 1536);
  };

  // ---------------- t = 0 prologue ----------------
  {
    const unsigned short* gxr = gx + (size_t)bg * G4 + g * HSL + jd;
    gxv0 = *(const unsigned*)(gxr);
    gxv1 = *(const unsigned*)(gxr + 512);
    gxv2 = *(const unsigned*)(gxr + 1024);
    gxv3 = *(const unsigned*)(gxr + 1536);
    int iv = -1;
    if (tid < NB * 3){
      int b = tid / 3, k = tid - b * 3;
      iv = prev_idx[(size_t)(grp * NB + b) * (SS * KKK) + 1 * KKK + k];
      ist2[1][tid] = iv;
      wst2[1][tid] = prev_w[(size_t)(grp * NB + b) * (SS * KKK) + 1 * KKK + k];
    }
    if (tid < 64){
      int m = iv;
      #pragma unroll
      for (int off = 32; off; off >>= 1) m = max(m, __shfl_xor(m, off));
      if (tid == 0) mneed2[1] = m;
    }
    float cn0 = sigm(blo(gxv0)) * tanh_(blo(gxv2));
    float cn1 = sigm(bhi(gxv0)) * tanh_(bhi(gxv2));
    float hn0 = sigm(blo(gxv3)) * tanh_(cn0);
    float hn1 = sigm(bhi(gxv3)) * tanh_(cn1);
    *(float2*)(c_hist + cblk + (size_t)cb * HSL + jd) = make_float2(cn0, cn1);
    unsigned hv = f2bf(hn0) | (f2bf(hn1) << 16);
    __hip_atomic_store(hbw + (((((size_t)grp * GS + g) * NB + cb) * HSL + jd) >> 1), hv,
                       __ATOMIC_RELAXED, __HIP_MEMORY_SCOPE_AGENT);
    if (0 >= st && 0 < en){ pm0 = fmaxf(pm0, hn0); pm1 = fmaxf(pm1, hn1); }
    __syncthreads();   // drains h/c stores; publishes ist2[1]/mneed2[1] block-wide
    if (tid == 0){
      __hip_atomic_store(&tags[grp * GS + g], 1u, __ATOMIC_RELAXED, __HIP_MEMORY_SCOPE_AGENT);
      wm_l[g] = 1;
    }
    issue_cgx(1, 1);
  }
  bool valid = false;   // first-step gather always via fallback (peers' wm unknown)

  // ---------------- main loop ----------------
  for (int t = 1; t < SS; t++){
    const int sl = t & 1, sn = sl ^ 1;

    // [S] pipelined tag snapshot: issue now, staged to snap_l in [C]
    unsigned tsnap = 0;
    if (tid < GS)
      tsnap = __hip_atomic_load(&tags[grp * GS + tid], __ATOMIC_RELAXED,
                                __HIP_MEMORY_SCOPE_AGENT);

    // [A] blocking poll only when prefetch wasn't validated (true fresh deps);
    //     own tag always covers need (<= t), so skip tid == g
    if (!valid){
      const int need = mneed2[sl] + 1;
      if (tid < GS && tid != g){
        int v = wm_l[tid];
        if (v < need){
          const unsigned int* tp = tags + grp * GS + tid;
          do {
            v = (int)__hip_atomic_load(tp, __ATOMIC_RELAXED, __HIP_MEMORY_SCOPE_AGENT);
            if (v < need) __builtin_amdgcn_s_sleep(1);
          } while (v < need);
          wm_l[tid] = v;
        }
      }
      __syncthreads();
      issue_gather(sl);
    }

    // [B] weight + pack h~ -> hA (XOR-swizzled)
    {
      float w0 = wst2[sl][gq * 3], w1 = wst2[sl][gq * 3 + 1], w2 = wst2[sl][gq * 3 + 2];
      unsigned pk[8];
      #pragma unroll
      for (int j = 0; j < 4; j++){
        unsigned a_lo = (unsigned)dq0[j], a_hi = (unsigned)(dq0[j] >> 32);
        unsigned b_lo = (unsigned)dq1[j], b_hi = (unsigned)(dq1[j] >> 32);
        unsigned c_lo = (unsigned)dq2[j], c_hi = (unsigned)(dq2[j] >> 32);
        float l0 = w0 * blo(a_lo) + w1 * blo(b_lo) + w2 * blo(c_lo);
        float h0 = w0 * bhi(a_lo) + w1 * bhi(b_lo) + w2 * bhi(c_lo);
        float l1 = w0 * blo(a_hi) + w1 * blo(b_hi) + w2 * blo(c_hi);
        float h1 = w0 * bhi(a_hi) + w1 * bhi(b_hi) + w2 * bhi(c_hi);
        pk[2 * j]     = f2bf(l0) | (f2bf(h0) << 16);
        pk[2 * j + 1] = f2bf(l1) | (f2bf(h1) << 16);
      }
      int ob = (gq << 10) + gd * 32;
      int xr = (gq & 7) << 4;
      *(uint4*)(hA + (ob ^ xr))        = (uint4){pk[0], pk[1], pk[2], pk[3]};
      *(uint4*)(hA + ((ob + 16) ^ xr)) = (uint4){pk[4], pk[5], pk[6], pk[7]};
    }
    __syncthreads();

    // [C] ist/wst(t+1) load + MFMA + snapshot staging
    int iv = -1;
    if (t + 1 < SS){
      if (tid < NB * 3){
        int b = tid / 3, k = tid - b * 3;
        iv = prev_idx[(size_t)(grp * NB + b) * (SS * KKK) + (t + 1) * KKK + k];
        ist2[sn][tid] = iv;
        wst2[sn][tid] = prev_w[(size_t)(grp * NB + b) * (SS * KKK) + (t + 1) * KKK + k];
      }
    }
    {
      f32x4 p00 = {0,0,0,0}, p01 = {0,0,0,0}, p10 = {0,0,0,0}, p11 = {0,0,0,0};
      const int rA = lane & 15;
      const int kb = (lane >> 4) << 4;
      const int xr = (rA & 7) << 4;
      const int rbase = rA << 10;
      #pragma unroll
      for (int kf = 0; kf < 16; kf += 2){
        bf16x8 a0 = *(const bf16x8*)(hA + ((rbase + kf * 64 + kb) ^ xr));
        bf16x8 a1 = *(const bf16x8*)(hA + ((rbase + (kf + 1) * 64 + kb) ^ xr));
        p00 = __builtin_amdgcn_mfma_f32_16x16x32_bf16(a0, bfr0[kf],     p00, 0, 0, 0);
        p10 = __builtin_amdgcn_mfma_f32_16x16x32_bf16(a0, bfr1[kf],     p10, 0, 0, 0);
        p01 = __builtin_amdgcn_mfma_f32_16x16x32_bf16(a1, bfr0[kf + 1], p01, 0, 0, 0);
        p11 = __builtin_amdgcn_mfma_f32_16x16x32_bf16(a1, bfr1[kf + 1], p11, 0, 0, 0);
      }
      int cl0 = (2 * w) * 16 + rA, cl1 = cl0 + 16;
      #pragma unroll
      for (int j = 0; j < 4; j++){
        int bq = ((lane >> 4) << 2) + j;
        gex[bq][cl0] = p00[j] + p01[j];
        gex[bq][cl1] = p10[j] + p11[j];
      }
    }
    if (t + 1 < SS && tid < 64){
      int m = iv;
      #pragma unroll
      for (int off = 32; off; off >>= 1) m = max(m, __shfl_xor(m, off));
      if (tid == 0) mneed2[sn] = m;
    }
    if (tid < GS) snap_l[tid] = (int)tsnap;
    __syncthreads();

    // [V] all-thread validation + EARLY validated gather issue (hidden under [D]).
    //     Own coverage is exactly t (rows <= t-1 written & drained; row t comes in [D]).
    //     snap_l[g] == t (own tag at loop top), so including p==g caps m at t: safe.
    bool validn = false;
    if (t + 1 < SS){
      const int need = mneed2[sn] + 1;
      int m = max(wm_l[0], snap_l[0]);
      #pragma unroll
      for (int p = 1; p < GS; p++) m = min(m, max(wm_l[p], snap_l[p]));
      validn = (m >= need);
      if (validn) issue_gather(sn);
    }

    // [D] elementwise LSTM cell (gex LDS + prefetched gx/c regs) + stores
    {
      float w0 = wst2[sl][cb * 3], w1 = wst2[sl][cb * 3 + 1], w2 = wst2[sl][cb * 3 + 2];
      float g_i0 = blo(gxv0) + gex[cb][jd];
      float g_i1 = bhi(gxv0) + gex[cb][jd + 1];
      float g_f0 = blo(gxv1) + gex[cb][64 + jd];
      float g_f1 = bhi(gxv1) + gex[cb][64 + jd + 1];
      float g_g0 = blo(gxv2) + gex[cb][128 + jd];
      float g_g1 = bhi(gxv2) + gex[cb][128 + jd + 1];
      float g_o0 = blo(gxv3) + gex[cb][192 + jd];
      float g_o1 = bhi(gxv3) + gex[cb][192 + jd + 1];
      float co0 = w0 * cg0.x + w1 * cg1.x + w2 * cg2.x;
      float co1 = w0 * cg0.y + w1 * cg1.y + w2 * cg2.y;
      float cn0 = sigm(g_f0) * co0 + sigm(g_i0) * tanh_(g_g0);
      float cn1 = sigm(g_f1) * co1 + sigm(g_i1) * tanh_(g_g1);
      float hn0 = sigm(g_o0) * tanh_(cn0);
      float hn1 = sigm(g_o1) * tanh_(cn1);
      *(float2*)(c_hist + cblk + ((size_t)t * NB + cb) * HSL + jd) = make_float2(cn0, cn1);
      unsigned hv = f2bf(hn0) | (f2bf(hn1) << 16);
      __hip_atomic_store(hbw + ((((((size_t)t * NG + grp) * GS + g) * NB + cb) * HSL + jd) >> 1),
                         hv, __ATOMIC_RELAXED, __HIP_MEMORY_SCOPE_AGENT);
      if (t >= st && t < en){ pm0 = fmaxf(pm0, hn0); pm1 = fmaxf(pm1, hn1); }
    }
    // fold snapshot into watermarks (for next step's [A]/[V])
    if (tid < GS) wm_l[tid] = max(wm_l[tid], snap_l[tid]);
    __syncthreads();   // compiler drains vmcnt(0) -> h/c stores visible before tag

    // [E] publish + own-block prefetch for t+1
    if (tid == 0)
      __hip_atomic_store(&tags[grp * GS + g], (unsigned)(t + 1),
                         __ATOMIC_RELAXED, __HIP_MEMORY_SCOPE_AGENT);
    if (t + 1 < SS)
      issue_cgx(sn, t + 1);          // own-block data: always safe
    valid = validn;
  }

  pooled[(size_t)bg * HH + g * HSL + jd]     = (en > st && pm0 > -1e29f) ? pm0 : 0.f;
  pooled[(size_t)bg * HH + g * HSL + jd + 1] = (en > st && pm1 > -1e29f) ? pm1 : 0.f;
}

// ---------------- pool_lin ----------------
__global__ __launch_bounds__(128) void pool_lin(
    const float* __restrict__ pooled, const float* __restrict__ W_lin,
    const float* __restrict__ b_lin, float* __restrict__ out)
{
  __shared__ float p[HH];
  int b = blockIdx.x, tid = threadIdx.x;
  *(float4*)&p[tid * 4] = *(const float4*)&pooled[(size_t)b * HH + tid * 4];
  __syncthreads();
  float acc = b_lin[tid];
  const float* wr = W_lin + (size_t)tid * HH;
  #pragma unroll 8
  for (int h = 0; h < HH; h += 4){
    float4 w = *(const float4*)(wr + h);
    acc += w.x * p[h] + w.y * p[h+1] + w.z * p[h+2] + w.w * p[h+3];
  }
  out[b * LL + tid] = acc;
}

extern "C" void kernel_launch(void* const* d_in, const int* in_sizes, int n_in,
                              void* d_out, int out_size, void* d_ws, size_t ws_size,
                              hipStream_t stream)
{
  (void)in_sizes; (void)n_in; (void)out_size; (void)ws_size;
  const int*   inputs    = (const int*)  d_in[0];
  const int*   positions = (const int*)  d_in[1];
  const int*   prev_idx  = (const int*)  d_in[2];
  const float* prev_w    = (const float*)d_in[3];
  const float* emb       = (const float*)d_in[4];
  const float* Wih       = (const float*)d_in[5];
  const float* Whh       = (const float*)d_in[6];
  const float* bih       = (const float*)d_in[7];
  const float* bhh       = (const float*)d_in[8];
  const float* W_lin     = (const float*)d_in[9];
  const float* b_lin     = (const float*)d_in[10];
  float* out = (float*)d_out;
  char* ws = (char*)d_ws;

  unsigned int*   tags   = (unsigned int*)  ws;                 // 64 B
  unsigned short* Xb     = (unsigned short*)(ws + 4096);        // 8 MB
  unsigned short* Wihb   = (unsigned short*)(ws + 8392704);     // 2 MB
  float*          bias   = (float*)         (ws + 10489856);    // 8 KB
  unsigned short* gx     = (unsigned short*)(ws + 10498048);    // 32 MB
  unsigned short* h_hist = (unsigned short*)(ws + 44052480);    // 8 MB  [S][NG][GS][NB][HSL]
  float*          c_hist = (float*)         (ws + 52441088);    // 16 MB [16][S][NB][HSL]
  float*          pooled = (float*)         (ws + 69218304);    // 64 KB

  hipMemsetAsync(tags, 0, 4096, stream);
  prep_kernel<<<641, 256, 0, stream>>>(inputs, emb, Wih, bih, bhh, Xb, Wihb, bias);
  gemm_gx<<<dim3(64, 16), 256, 0, stream>>>(Xb, Wihb, bias, gx);
  recur9<<<16, 512, 0, stream>>>(prev_idx, prev_w, Whh, positions, gx, h_hist, c_hist, pooled, tags);
  pool_lin<<<32, 128, 0, stream>>>(pooled, W_lin, b_lin, out);
}